// Round 10
// baseline (365.028 us; speedup 1.0000x reference)
//
#include <hip/hip_runtime.h>

// out[s][o] = sum_i x[s][i] * dq(w[o][i]); int4 group quant, group=256, scale=max(absmax/7,1e-9)
// x: [16,4096] f32, w: [14336,4096] f32 (235 MB streamed once), out: [16,14336] f32
//
// R11 = R10 + __launch_bounds__(NTHR, 2). Single change.
// R10 post-mortem: 142us, VGPR_Count=60 — but acc[4][16] alone is 64 live
// floats (+wq/addr ~ 90+ demand) and WRITE_SIZE shows zero scratch. The only
// home for the accumulators is the AGPR half of gfx950's unified RF: the
// allocator squeezed VGPRs for 8-waves/EU occupancy and spilled acc to AGPRs,
// so every fmaf pays v_accvgpr_read + fma + v_accvgpr_write (~3x VALU + dep
// latency). Cross-check: est. issue cycles x3 matches VALUBusy 31%. Same
// pattern (VGPR=52 with 32+ live accs) poisoned R8/R9 — the 3-4x gap above
// pipe floors in EVERY variant was AGPR round-trip tax, while the occupancy
// it bought (8 w/EU) is unreachable (grid ~3.5 blocks/CU).
// Fix: min-waves/EU=2 -> VGPR budget 512/2=256; acc lives in real VGPRs.
// At ~128 VGPR the HW still fits 4 blocks/CU >= grid's 3.5 -> no occupancy
// cost. Everything else identical to R10 (no LDS, no barriers, RPW=4,
// '#pragma unroll 1' on G-loop per R7's 263MB-scratch lesson, DPP absmax,
// value-split epilogue).
// Watch: VGPR_Count must jump to ~100-140 (pass/fail for this theory);
// WRITE_SIZE must stay ~0.9MB (scratch tripwire).

constexpr int O_DIM  = 14336;
constexpr int I_DIM  = 4096;
constexpr int S_DIM  = 16;
constexpr int GS     = 256;           // quant group size
constexpr int NG     = I_DIM / GS;    // 16 groups
constexpr int RPW    = 4;             // rows per wave
constexpr int NWAVE  = 4;             // waves per block
constexpr int NTHR   = 64 * NWAVE;    // 256
constexpr int RPB    = RPW * NWAVE;   // 16 rows/block -> 896 blocks

// wave64 max-reduce on the VALU pipe (validated correct in R5..R10 runs):
// 4x row_shr + row_bcast15 + row_bcast31, readlane(63) -> wave-uniform SGPR.
// Inputs >= 0, so bound_ctrl=true zero-fill is identity for max.
__device__ __forceinline__ float wave_max_dpp(float x) {
    int v = __float_as_int(x);
    int t;
    t = __builtin_amdgcn_update_dpp(0, v, 0x111, 0xf, 0xf, true); // row_shr:1
    v = __float_as_int(fmaxf(__int_as_float(v), __int_as_float(t)));
    t = __builtin_amdgcn_update_dpp(0, v, 0x112, 0xf, 0xf, true); // row_shr:2
    v = __float_as_int(fmaxf(__int_as_float(v), __int_as_float(t)));
    t = __builtin_amdgcn_update_dpp(0, v, 0x114, 0xf, 0xf, true); // row_shr:4
    v = __float_as_int(fmaxf(__int_as_float(v), __int_as_float(t)));
    t = __builtin_amdgcn_update_dpp(0, v, 0x118, 0xf, 0xf, true); // row_shr:8
    v = __float_as_int(fmaxf(__int_as_float(v), __int_as_float(t)));
    t = __builtin_amdgcn_update_dpp(0, v, 0x142, 0xf, 0xf, true); // row_bcast:15
    v = __float_as_int(fmaxf(__int_as_float(v), __int_as_float(t)));
    t = __builtin_amdgcn_update_dpp(0, v, 0x143, 0xf, 0xf, true); // row_bcast:31
    v = __float_as_int(fmaxf(__int_as_float(v), __int_as_float(t)));
    return __int_as_float(__builtin_amdgcn_readlane(v, 63));
}

__global__ __launch_bounds__(NTHR, 2)
void qlin_kernel(const float* __restrict__ x,
                 const float* __restrict__ w,
                 float* __restrict__ out)
{
    const int tid  = threadIdx.x;
    const int lane = tid & 63;
    const int wv   = tid >> 6;          // 0..NWAVE-1
    const int row0 = blockIdx.x * RPB + wv * RPW;

    const float* wp = w + (size_t)row0 * I_DIM + lane * 4;
    const float* xp = x + lane * 4;     // + s*I_DIM + G*GS per use

    float acc[RPW][S_DIM];
#pragma unroll
    for (int r = 0; r < RPW; ++r)
#pragma unroll
        for (int s = 0; s < S_DIM; ++s) acc[r][s] = 0.0f;

    // unroll 1: R7 lesson — cross-iteration hoisting of global loads blew the
    // 128-VGPR cap -> 263 MB scratch spill. Keep the loop body pinned.
#pragma unroll 1
    for (int G = 0; G < NG; ++G) {
        // w for this group: 4 coalesced dwordx4 per wave (the HBM stream).
        float4 wq[RPW];
#pragma unroll
        for (int r = 0; r < RPW; ++r)
            wq[r] = *reinterpret_cast<const float4*>(
                wp + (size_t)r * I_DIM + G * GS);

        // dequant in place; absmax on VALU pipe via DPP. The serial DPP chain
        // also gives the scheduler room to batch the upcoming x loads.
#pragma unroll
        for (int r = 0; r < RPW; ++r) {
            float4 v = wq[r];
            float m = fmaxf(fmaxf(fabsf(v.x), fabsf(v.y)),
                            fmaxf(fabsf(v.z), fabsf(v.w)));
            m = wave_max_dpp(m);
            float scale = fmaxf(m * (1.0f / 7.0f), 1e-9f);
            float invs  = 1.0f / scale;
            // clamp provably dead: scale >= absmax/7 => |v*invs| <= 7
            wq[r].x = rintf(v.x * invs) * scale;
            wq[r].y = rintf(v.y * invs) * scale;
            wq[r].z = rintf(v.z * invs) * scale;
            wq[r].w = rintf(v.w * invs) * scale;
        }

        // FMA: x straight from global (L1/L2-hit; x slice per group = 16 KB,
        // L1-resident; whole x = 256 KB, L2-resident). 16 dwordx4 per iter.
        const float* xg = xp + G * GS;
#pragma unroll
        for (int s = 0; s < S_DIM; ++s) {
            float4 xv = *reinterpret_cast<const float4*>(
                &xg[(size_t)s * I_DIM]);
#pragma unroll
            for (int r = 0; r < RPW; ++r) {
                acc[r][s] = fmaf(wq[r].x, xv.x, acc[r][s]);
                acc[r][s] = fmaf(wq[r].y, xv.y, acc[r][s]);
                acc[r][s] = fmaf(wq[r].z, xv.z, acc[r][s]);
                acc[r][s] = fmaf(wq[r].w, xv.w, acc[r][s]);
            }
        }
    }

    // ---- epilogue: reduce 64 accs across 64 lanes in 63 shuffles ----
    // value-splitting butterfly (validated in R6/R10 passing runs); lane l
    // ends with the sum of a[l], l = (r<<4)|s.
    float a[64];
#pragma unroll
    for (int r = 0; r < RPW; ++r)
#pragma unroll
        for (int s = 0; s < S_DIM; ++s) a[(r << 4) | s] = acc[r][s];

#pragma unroll
    for (int m = 32; m >= 1; m >>= 1) {
        const bool hi = (lane & m) != 0;
#pragma unroll
        for (int j = 0; j < m; ++j) {
            float snd  = hi ? a[j] : a[j + m];
            float rcv  = __shfl_xor(snd, m, 64);
            float kept = hi ? a[j + m] : a[j];
            a[j] = kept + rcv;
        }
    }
    {
        const int r = lane >> 4, s = lane & 15;
        out[s * O_DIM + (row0 + r)] = a[0];
    }
}

extern "C" void kernel_launch(void* const* d_in, const int* in_sizes, int n_in,
                              void* d_out, int out_size, void* d_ws, size_t ws_size,
                              hipStream_t stream) {
    const float* x = (const float*)d_in[0];   // 1*16*4096
    const float* w = (const float*)d_in[1];   // 14336*4096
    float* out = (float*)d_out;               // 16*14336
    dim3 grid(O_DIM / RPB);                   // 896 blocks
    dim3 block(NTHR);                         // 256 = 4 waves
    qlin_kernel<<<grid, block, 0, stream>>>(x, w, out);
}